// Round 2
// baseline (133.411 us; speedup 1.0000x reference)
//
#include <hip/hip_runtime.h>
#include <hip/hip_bf16.h>

typedef __bf16 bf16x8 __attribute__((ext_vector_type(8)));
typedef float f32x4 __attribute__((ext_vector_type(4)));
typedef float f32x16 __attribute__((ext_vector_type(16)));
typedef unsigned int uint2v __attribute__((ext_vector_type(2)));

#define MFMA16 __builtin_amdgcn_mfma_f32_16x16x32_bf16
#define MFMA32 __builtin_amdgcn_mfma_f32_32x32x16_bf16

__device__ __forceinline__ unsigned short f2b(float f) {
  unsigned int u = __float_as_uint(f);
  u += 0x7FFFu + ((u >> 16) & 1u);
  return (unsigned short)(u >> 16);
}

__device__ __forceinline__ float b2f(unsigned short s) {
  return __uint_as_float(((unsigned)s) << 16);
}

union U128 {
  uint4 u;
  unsigned short s[8];
  bf16x8 b;
};

union BPack {
  __hip_bfloat162 h2;
  unsigned u;
};

__device__ __forceinline__ unsigned packbf(float a, float b) {
  BPack p;
  p.h2 = __float22bfloat162_rn(make_float2(a, b));
  return p.u;
}

// ---------------- projection via MFMA ----------------
// grid 512 = (b = blk&7, n0 = 64-tile). block 256 (4 waves).
// Y[96 pad][4096] = W[96x64] X[64x4096] per batch, bf16 MFMA 16x16x32.
// wq rows pre-scaled by log2(e) so attention uses native exp2.
// h stored BLOCKED: h_blk[b][n>>3][c][n&7] -> attention PV A-fragments
// are lane-contiguous 16B groups (coalesced).
__global__ __launch_bounds__(256, 2) void proj_kernel(
    const float* __restrict__ x, const float* __restrict__ wq,
    const float* __restrict__ wk, const float* __restrict__ wv_w,
    unsigned short* __restrict__ f_t, unsigned short* __restrict__ g_t,
    unsigned short* __restrict__ h_out) {
  __shared__ unsigned short xT[64 * 64];
  __shared__ unsigned short wT[96 * 72];

  const int tid = (int)threadIdx.x;
  const int wvp = tid >> 6;
  const int lane = tid & 63;
  const int b = (int)blockIdx.x & 7;
  const int n0 = ((int)blockIdx.x >> 3) << 6;

  // ---- stage xT: thread loads 16 c's for n=lane, packs, swizzled write ----
  {
    const float* xb = x + ((size_t)b << 18) + n0 + lane;
    const int c0 = wvp * 16;
    float xv[16];
#pragma unroll
    for (int cc = 0; cc < 16; ++cc) xv[cc] = xb[(size_t)(c0 + cc) << 12];
#pragma unroll
    for (int p = 0; p < 4; ++p) {
      const int c = c0 + 4 * p;
      uint2 d;
      d.x = packbf(xv[4 * p + 0], xv[4 * p + 1]);
      d.y = packbf(xv[4 * p + 2], xv[4 * p + 3]);
      const int g = c >> 3;
      const int idx = lane * 64 + (((g ^ (lane & 7)) << 3) | (((c >> 2) & 1) << 2));
      *(uint2*)&xT[idx] = d;
    }
  }
  // ---- stage wT (80 rows of 64, bf16); wq scaled by log2(e) ----
#pragma unroll
  for (int i = 0; i < 20; ++i) {
    const int idx = i * 256 + tid;
    const float wval = (idx < 512) ? wq[idx] * 1.44269504f
                     : (idx < 1024) ? wk[idx - 512]
                                    : wv_w[idx - 1024];
    wT[(idx >> 6) * 72 + (idx & 63)] = f2b(wval);
  }
  __syncthreads();

  // ---- compute ----
  const int t = lane & 15, q = lane >> 4;
  const int nloc = wvp * 16 + t;
  U128 Bf[2];
#pragma unroll
  for (int kp = 0; kp < 2; ++kp) {
    const int g = kp * 4 + q;
    Bf[kp].u = *(const uint4*)&xT[nloc * 64 + ((g ^ (nloc & 7)) << 3)];
  }
  const int nabs = n0 + nloc;
#pragma unroll
  for (int rt = 0; rt < 5; ++rt) {
    f32x4 acc = {0.f, 0.f, 0.f, 0.f};
#pragma unroll
    for (int kp = 0; kp < 2; ++kp) {
      U128 Af;
      Af.u = *(const uint4*)&wT[(rt * 16 + t) * 72 + ((kp * 4 + q) << 3)];
      acc = MFMA16(Af.b, Bf[kp].b, acc, 0, 0, 0);
    }
#pragma unroll
    for (int reg = 0; reg < 4; ++reg) {
      const int r = rt * 16 + 4 * q + reg;
      const unsigned short v = f2b(acc[reg]);
      if (r < 8)
        f_t[((size_t)((b << 12) + nabs) << 3) + r] = v;
      else if (r < 16)
        g_t[((size_t)((b << 12) + nabs) << 3) + (r - 8)] = v;
      else
        h_out[((size_t)b << 18) + ((size_t)(nabs >> 3) << 9) +
              ((r - 16) << 3) + (nabs & 7)] = v;
    }
  }
}

// ---------------- flash attention ------------------------------------------
// grid 1024 = (b = blk&7, m32-tile). block 256 (4 waves, independent).
// R9: score-MFMA software pipeline. Body for tile k consumes S_k (computed
// during body k-1, right after its exps) and produces S_{k+1}; the score
// MFMA latency hides under the previous body's pack/PV section instead of
// stalling the exp chain. F prefetched 2 tiles deep (4 static slots,
// unroll-4 loop -> no register rotation movs); H stays 1 tile deep.
// s_setprio(1) wrapped around MFMA clusters (T5, +4-7% on this structure).
__global__ __launch_bounds__(256, 4) void attn_kernel(
    const unsigned short* __restrict__ f_t, const unsigned short* __restrict__ g_t,
    const unsigned short* __restrict__ h, const float* __restrict__ x,
    const float* __restrict__ gamma, float* __restrict__ out) {
  __shared__ unsigned short Opart[4][32][66];  // [wave][m][c], bf16, 16.9 KB
  __shared__ float lred[4][32];
  __shared__ float lsum[32];

  const int tid = (int)threadIdx.x;
  const int wave = tid >> 6;
  const int lane = tid & 63;
  const int ml = lane & 31;
  const int hh = lane >> 5;

  const int b = (int)blockIdx.x & 7;
  const int m32 = ((int)blockIdx.x >> 3) << 5;

  const unsigned short* fb = f_t + ((size_t)b << 15);
  const unsigned short* hb = h + ((size_t)b << 18);  // blocked layout

  U128 G;
  G.u = make_uint4(0u, 0u, 0u, 0u);
  if (hh == 0) G.u = *(const uint4*)(g_t + ((size_t)((b << 12) + m32 + ml) << 3));

  f32x16 O0 = {}, O1 = {};
  float lp = 0.f;
  const f32x16 ZC = {};  // persistent zero C operand (hoisted)

  const int nbase = wave << 10;

  const unsigned short* fp = fb + ((size_t)(nbase + ml) << 3);
  const unsigned short* hp = hb + ((nbase >> 3) << 9) + (hh << 9) + (ml << 3);

  // F slots (2-tile-deep prefetch), H ping-pong, S ping-pong
  U128 F_A, F_B, F_C, F_D, Ha_e[4], Ha_o[4];
  f32x16 S_e, S_o;

  // prologue: F tiles 0,1; H tile 0; S for tile 0
  F_A.u = *(const uint4*)(fp);
  F_B.u = *(const uint4*)(fp + 256);
  Ha_e[0].u = *(const uint4*)(hp);
  Ha_e[1].u = *(const uint4*)(hp + 256);
  Ha_e[2].u = *(const uint4*)(hp + 1024);
  Ha_e[3].u = *(const uint4*)(hp + 1280);
  __builtin_amdgcn_s_setprio(1);
  S_e = MFMA32(F_A.b, G.b, ZC, 0, 0, 0);
  __builtin_amdgcn_s_setprio(0);

  // body: consume Sc (tile k), produce Sn (tile k+1) from Fn, PV with Hv.
  auto body = [&](const f32x16& Sc, const U128* Hv, const U128& Fn, f32x16& Sn,
                  bool produce) {
    float e[16];
#pragma unroll
    for (int r = 0; r < 16; ++r) e[r] = __builtin_amdgcn_exp2f(Sc[r]);
    if (produce) {
      __builtin_amdgcn_s_setprio(1);
      Sn = MFMA32(Fn.b, G.b, ZC, 0, 0, 0);
      __builtin_amdgcn_s_setprio(0);
    }
    lp += (((e[0] + e[1]) + (e[2] + e[3])) + ((e[4] + e[5]) + (e[6] + e[7]))) +
          (((e[8] + e[9]) + (e[10] + e[11])) + ((e[12] + e[13]) + (e[14] + e[15])));
#pragma unroll
    for (int kt = 0; kt < 2; ++kt) {
      const unsigned A0 = packbf(e[8 * kt + 0], e[8 * kt + 1]);
      const unsigned A1 = packbf(e[8 * kt + 2], e[8 * kt + 3]);
      const unsigned B0 = packbf(e[8 * kt + 4], e[8 * kt + 5]);
      const unsigned B1 = packbf(e[8 * kt + 6], e[8 * kt + 7]);
      const uint2v r0 = __builtin_amdgcn_permlane32_swap(A0, B0, false, false);
      const uint2v r1 = __builtin_amdgcn_permlane32_swap(A1, B1, false, false);
      U128 P;
      P.u.x = r0[0];
      P.u.y = r1[0];
      P.u.z = r0[1];
      P.u.w = r1[1];
      __builtin_amdgcn_s_setprio(1);
      O0 = MFMA32(Hv[2 * kt + 0].b, P.b, O0, 0, 0, 0);
      O1 = MFMA32(Hv[2 * kt + 1].b, P.b, O1, 0, 0, 0);
      __builtin_amdgcn_s_setprio(0);
    }
  };

  // main loop: 4 tiles per iter (tiles 4j..4j+3), j=0..6; tiles 28..31 peeled.
#pragma unroll 1
  for (int j = 0; j < 7; ++j) {
    // --- phase 1: tiles 4j, 4j+1 ---
    F_C.u = *(const uint4*)(fp + 512);   // F tile 4j+2
    F_D.u = *(const uint4*)(fp + 768);   // F tile 4j+3
    Ha_o[0].u = *(const uint4*)(hp + 2048);   // H tile 4j+1
    Ha_o[1].u = *(const uint4*)(hp + 2304);
    Ha_o[2].u = *(const uint4*)(hp + 3072);
    Ha_o[3].u = *(const uint4*)(hp + 3328);
    body(S_e, Ha_e, F_B, S_o, true);          // tile 4j -> S(4j+1)
    Ha_e[0].u = *(const uint4*)(hp + 4096);   // H tile 4j+2
    Ha_e[1].u = *(const uint4*)(hp + 4352);
    Ha_e[2].u = *(const uint4*)(hp + 5120);
    Ha_e[3].u = *(const uint4*)(hp + 5376);
    body(S_o, Ha_o, F_C, S_e, true);          // tile 4j+1 -> S(4j+2)
    // --- phase 2: tiles 4j+2, 4j+3 ---
    F_A.u = *(const uint4*)(fp + 1024);  // F tile 4j+4
    F_B.u = *(const uint4*)(fp + 1280);  // F tile 4j+5
    Ha_o[0].u = *(const uint4*)(hp + 6144);   // H tile 4j+3
    Ha_o[1].u = *(const uint4*)(hp + 6400);
    Ha_o[2].u = *(const uint4*)(hp + 7168);
    Ha_o[3].u = *(const uint4*)(hp + 7424);
    body(S_e, Ha_e, F_D, S_o, true);          // tile 4j+2 -> S(4j+3)
    Ha_e[0].u = *(const uint4*)(hp + 8192);   // H tile 4j+4
    Ha_e[1].u = *(const uint4*)(hp + 8448);
    Ha_e[2].u = *(const uint4*)(hp + 9216);
    Ha_e[3].u = *(const uint4*)(hp + 9472);
    body(S_o, Ha_o, F_A, S_e, true);          // tile 4j+3 -> S(4j+4)
    fp += 1024;
    hp += 8192;
  }
  // --- tail: tiles 28..31 (H(28) already loaded; F_B holds F(29)) ---
  F_C.u = *(const uint4*)(fp + 512);   // F tile 30
  F_D.u = *(const uint4*)(fp + 768);   // F tile 31
  Ha_o[0].u = *(const uint4*)(hp + 2048);   // H tile 29
  Ha_o[1].u = *(const uint4*)(hp + 2304);
  Ha_o[2].u = *(const uint4*)(hp + 3072);
  Ha_o[3].u = *(const uint4*)(hp + 3328);
  body(S_e, Ha_e, F_B, S_o, true);          // tile 28 -> S(29)
  Ha_e[0].u = *(const uint4*)(hp + 4096);   // H tile 30
  Ha_e[1].u = *(const uint4*)(hp + 4352);
  Ha_e[2].u = *(const uint4*)(hp + 5120);
  Ha_e[3].u = *(const uint4*)(hp + 5376);
  body(S_o, Ha_o, F_C, S_e, true);          // tile 29 -> S(30)
  Ha_o[0].u = *(const uint4*)(hp + 6144);   // H tile 31
  Ha_o[1].u = *(const uint4*)(hp + 6400);
  Ha_o[2].u = *(const uint4*)(hp + 7168);
  Ha_o[3].u = *(const uint4*)(hp + 7424);
  body(S_e, Ha_e, F_D, S_o, true);          // tile 30 -> S(31)
  body(S_o, Ha_o, F_D, S_o, false);         // tile 31 (no produce)

  // wave-local denominator (both halves), then stash partials (bf16 pairs)
  lp += __shfl_xor(lp, 32, 64);
  if (hh == 0) lred[wave][ml] = lp;
#pragma unroll
  for (int r = 0; r < 8; ++r) {
    const int c0 = ((2 * r) & 3) + 8 * (r >> 1) + 4 * hh;
    *(unsigned*)&Opart[wave][ml][c0] = packbf(O0[2 * r], O0[2 * r + 1]);
    *(unsigned*)&Opart[wave][ml][c0 + 32] = packbf(O1[2 * r], O1[2 * r + 1]);
  }
  __syncthreads();
  if (tid < 32)
    lsum[tid] = (lred[0][tid] + lred[1][tid]) + (lred[2][tid] + lred[3][tid]);
  __syncthreads();

  // epilogue: thread owns c = tid>>2, m = (tid&3)*8 .. +8 (vectorized global)
  const int c = tid >> 2;
  const int m0l = (tid & 3) << 3;
  const float gam = gamma[0];
  float a[8];
#pragma unroll
  for (int j = 0; j < 8; ++j) a[j] = 0.f;
#pragma unroll
  for (int w = 0; w < 4; ++w)
#pragma unroll
    for (int j = 0; j < 8; ++j) a[j] += b2f(Opart[w][m0l + j][c]);

  const f32x4 l0 = *(const f32x4*)&lsum[m0l];
  const f32x4 l1 = *(const f32x4*)&lsum[m0l + 4];
  const size_t oi = (((size_t)b * 64 + c) << 12) + m32 + m0l;
  f32x4 xo0 = *(const f32x4*)(x + oi);
  f32x4 xo1 = *(const f32x4*)(x + oi + 4);
#pragma unroll
  for (int j = 0; j < 4; ++j) {
    xo0[j] += gam / l0[j] * a[j];
    xo1[j] += gam / l1[j] * a[j + 4];
  }
  *(f32x4*)(out + oi) = xo0;
  *(f32x4*)(out + oi + 4) = xo1;
}

extern "C" void kernel_launch(void* const* d_in, const int* in_sizes, int n_in,
                              void* d_out, int out_size, void* d_ws, size_t ws_size,
                              hipStream_t stream) {
  (void)in_sizes; (void)n_in; (void)out_size; (void)ws_size;
  const float* x = (const float*)d_in[0];
  const float* wq = (const float*)d_in[1];
  const float* wk = (const float*)d_in[2];
  const float* wv = (const float*)d_in[3];
  const float* gamma = (const float*)d_in[4];
  float* out = (float*)d_out;

  // workspace: f_t [8][4096][8] bf16, g_t same, h_blk [8][512][64][8] bf16
  unsigned short* f_t = (unsigned short*)d_ws;
  unsigned short* g_t = f_t + (size_t)8 * 4096 * 8;
  unsigned short* h = g_t + (size_t)8 * 4096 * 8;

  proj_kernel<<<512, 256, 0, stream>>>(x, wq, wk, wv, f_t, g_t, h);
  attn_kernel<<<1024, 256, 0, stream>>>(f_t, g_t, h, x, gamma, out);
}

// Round 3
// 105.529 us; speedup vs baseline: 1.2642x; 1.2642x over previous
//
#include <hip/hip_runtime.h>
#include <hip/hip_bf16.h>

typedef __bf16 bf16x8 __attribute__((ext_vector_type(8)));
typedef float f32x4 __attribute__((ext_vector_type(4)));
typedef float f32x16 __attribute__((ext_vector_type(16)));
typedef unsigned int uint2v __attribute__((ext_vector_type(2)));

#define MFMA16 __builtin_amdgcn_mfma_f32_16x16x32_bf16
#define MFMA32 __builtin_amdgcn_mfma_f32_32x32x16_bf16

__device__ __forceinline__ unsigned short f2b(float f) {
  unsigned int u = __float_as_uint(f);
  u += 0x7FFFu + ((u >> 16) & 1u);
  return (unsigned short)(u >> 16);
}

__device__ __forceinline__ float b2f(unsigned short s) {
  return __uint_as_float(((unsigned)s) << 16);
}

union U128 {
  uint4 u;
  unsigned short s[8];
  bf16x8 b;
};

union BPack {
  __hip_bfloat162 h2;
  unsigned u;
};

__device__ __forceinline__ unsigned packbf(float a, float b) {
  BPack p;
  p.h2 = __float22bfloat162_rn(make_float2(a, b));
  return p.u;
}

// ---------------- projection via MFMA ----------------
// grid 512 = (b = blk&7, n0 = 64-tile). block 256 (4 waves).
// Y[96 pad][4096] = W[96x64] X[64x4096] per batch, bf16 MFMA 16x16x32.
// wq rows pre-scaled by log2(e) so attention uses native exp2.
// h stored BLOCKED: h_blk[b][n>>3][c][n&7] -> attention PV A-fragments
// are lane-contiguous 16B groups (coalesced).
__global__ __launch_bounds__(256, 2) void proj_kernel(
    const float* __restrict__ x, const float* __restrict__ wq,
    const float* __restrict__ wk, const float* __restrict__ wv_w,
    unsigned short* __restrict__ f_t, unsigned short* __restrict__ g_t,
    unsigned short* __restrict__ h_out) {
  __shared__ unsigned short xT[64 * 64];
  __shared__ unsigned short wT[96 * 72];

  const int tid = (int)threadIdx.x;
  const int wvp = tid >> 6;
  const int lane = tid & 63;
  const int b = (int)blockIdx.x & 7;
  const int n0 = ((int)blockIdx.x >> 3) << 6;

  // ---- stage xT: thread loads 16 c's for n=lane, packs, swizzled write ----
  {
    const float* xb = x + ((size_t)b << 18) + n0 + lane;
    const int c0 = wvp * 16;
    float xv[16];
#pragma unroll
    for (int cc = 0; cc < 16; ++cc) xv[cc] = xb[(size_t)(c0 + cc) << 12];
#pragma unroll
    for (int p = 0; p < 4; ++p) {
      const int c = c0 + 4 * p;
      uint2 d;
      d.x = packbf(xv[4 * p + 0], xv[4 * p + 1]);
      d.y = packbf(xv[4 * p + 2], xv[4 * p + 3]);
      const int g = c >> 3;
      const int idx = lane * 64 + (((g ^ (lane & 7)) << 3) | (((c >> 2) & 1) << 2));
      *(uint2*)&xT[idx] = d;
    }
  }
  // ---- stage wT (80 rows of 64, bf16); wq scaled by log2(e) ----
#pragma unroll
  for (int i = 0; i < 20; ++i) {
    const int idx = i * 256 + tid;
    const float wval = (idx < 512) ? wq[idx] * 1.44269504f
                     : (idx < 1024) ? wk[idx - 512]
                                    : wv_w[idx - 1024];
    wT[(idx >> 6) * 72 + (idx & 63)] = f2b(wval);
  }
  __syncthreads();

  // ---- compute ----
  const int t = lane & 15, q = lane >> 4;
  const int nloc = wvp * 16 + t;
  U128 Bf[2];
#pragma unroll
  for (int kp = 0; kp < 2; ++kp) {
    const int g = kp * 4 + q;
    Bf[kp].u = *(const uint4*)&xT[nloc * 64 + ((g ^ (nloc & 7)) << 3)];
  }
  const int nabs = n0 + nloc;
#pragma unroll
  for (int rt = 0; rt < 5; ++rt) {
    f32x4 acc = {0.f, 0.f, 0.f, 0.f};
#pragma unroll
    for (int kp = 0; kp < 2; ++kp) {
      U128 Af;
      Af.u = *(const uint4*)&wT[(rt * 16 + t) * 72 + ((kp * 4 + q) << 3)];
      acc = MFMA16(Af.b, Bf[kp].b, acc, 0, 0, 0);
    }
#pragma unroll
    for (int reg = 0; reg < 4; ++reg) {
      const int r = rt * 16 + 4 * q + reg;
      const unsigned short v = f2b(acc[reg]);
      if (r < 8)
        f_t[((size_t)((b << 12) + nabs) << 3) + r] = v;
      else if (r < 16)
        g_t[((size_t)((b << 12) + nabs) << 3) + (r - 8)] = v;
      else
        h_out[((size_t)b << 18) + ((size_t)(nabs >> 3) << 9) +
              ((r - 16) << 3) + (nabs & 7)] = v;
    }
  }
}

// ---------------- flash attention ------------------------------------------
// grid 1024 = (b = blk&7, m32-tile). block 256 (4 waves, independent).
// R10: in-place score pipeline. ONE persistent f32x16 S: body k's exps
// consume S (tile k, produced one body earlier), then the produce-MFMA for
// tile k+1 overwrites S in place (S is dead after the exps). Breaks the
// score-MFMA -> exp serial dependency with ZERO extra pipeline buffers —
// R9's S/F ping-pong depth spilled to scratch (WRITE_SIZE 86 MB); this
// keeps the proven R8 register shape (F x2, H ping-pong) + 16 regs for S.
// s_setprio(1) around MFMA clusters (T5, +4-7% on this structure).
__global__ __launch_bounds__(256, 4) void attn_kernel(
    const unsigned short* __restrict__ f_t, const unsigned short* __restrict__ g_t,
    const unsigned short* __restrict__ h, const float* __restrict__ x,
    const float* __restrict__ gamma, float* __restrict__ out) {
  __shared__ unsigned short Opart[4][32][66];  // [wave][m][c], bf16, 16.9 KB
  __shared__ float lred[4][32];
  __shared__ float lsum[32];

  const int tid = (int)threadIdx.x;
  const int wave = tid >> 6;
  const int lane = tid & 63;
  const int ml = lane & 31;
  const int hh = lane >> 5;

  const int b = (int)blockIdx.x & 7;
  const int m32 = ((int)blockIdx.x >> 3) << 5;

  const unsigned short* fb = f_t + ((size_t)b << 15);
  const unsigned short* hb = h + ((size_t)b << 18);  // blocked layout

  U128 G;
  G.u = make_uint4(0u, 0u, 0u, 0u);
  if (hh == 0) G.u = *(const uint4*)(g_t + ((size_t)((b << 12) + m32 + ml) << 3));

  f32x16 O0 = {}, O1 = {};
  float lp = 0.f;
  const f32x16 ZC = {};  // persistent zero C operand

  const int nbase = wave << 10;

  const unsigned short* fp = fb + ((size_t)(nbase + ml) << 3);      // +512/iter
  const unsigned short* hp = hb + ((nbase >> 3) << 9) + (hh << 9) + (ml << 3);  // +4096/iter

  // fragment slots: F ping-pong (2), H ping-pong (2x4), ONE persistent S
  U128 F0, F1, Ha_e[4], Ha_o[4];
  f32x16 S;

  // prologue: F tiles 0,1; H tile 0; S = scores(tile 0)
  F0.u = *(const uint4*)(fp);
  F1.u = *(const uint4*)(fp + 256);
  Ha_e[0].u = *(const uint4*)(hp);
  Ha_e[1].u = *(const uint4*)(hp + 256);
  Ha_e[2].u = *(const uint4*)(hp + 1024);
  Ha_e[3].u = *(const uint4*)(hp + 1280);
  __builtin_amdgcn_s_setprio(1);
  S = MFMA32(F0.b, G.b, ZC, 0, 0, 0);
  __builtin_amdgcn_s_setprio(0);

  // body: exps consume S (tile k); if produce, S <- scores(tile k+1) from Fn
  // (in place — S is dead after the exps); then pack + PV with Hv (tile k).
  auto body = [&](const U128* Hv, const U128& Fn, bool produce) {
    float e[16];
#pragma unroll
    for (int r = 0; r < 16; ++r) e[r] = __builtin_amdgcn_exp2f(S[r]);
    if (produce) {
      __builtin_amdgcn_s_setprio(1);
      S = MFMA32(Fn.b, G.b, ZC, 0, 0, 0);
      __builtin_amdgcn_s_setprio(0);
    }
    lp += (((e[0] + e[1]) + (e[2] + e[3])) + ((e[4] + e[5]) + (e[6] + e[7]))) +
          (((e[8] + e[9]) + (e[10] + e[11])) + ((e[12] + e[13]) + (e[14] + e[15])));
#pragma unroll
    for (int kt = 0; kt < 2; ++kt) {
      const unsigned A0 = packbf(e[8 * kt + 0], e[8 * kt + 1]);
      const unsigned A1 = packbf(e[8 * kt + 2], e[8 * kt + 3]);
      const unsigned B0 = packbf(e[8 * kt + 4], e[8 * kt + 5]);
      const unsigned B1 = packbf(e[8 * kt + 6], e[8 * kt + 7]);
      const uint2v r0 = __builtin_amdgcn_permlane32_swap(A0, B0, false, false);
      const uint2v r1 = __builtin_amdgcn_permlane32_swap(A1, B1, false, false);
      U128 P;
      P.u.x = r0[0];
      P.u.y = r1[0];
      P.u.z = r0[1];
      P.u.w = r1[1];
      __builtin_amdgcn_s_setprio(1);
      O0 = MFMA32(Hv[2 * kt + 0].b, P.b, O0, 0, 0, 0);
      O1 = MFMA32(Hv[2 * kt + 1].b, P.b, O1, 0, 0, 0);
      __builtin_amdgcn_s_setprio(0);
    }
  };

  // main loop: tiles 2j, 2j+1 for j=0..14; tiles 30,31 peeled.
#pragma unroll 1
  for (int j = 0; j < 15; ++j) {
    Ha_o[0].u = *(const uint4*)(hp + 2048);   // H tile 2j+1
    Ha_o[1].u = *(const uint4*)(hp + 2304);
    Ha_o[2].u = *(const uint4*)(hp + 3072);
    Ha_o[3].u = *(const uint4*)(hp + 3328);
    F0.u = *(const uint4*)(fp + 512);         // F tile 2j+2
    body(Ha_e, F1, true);                     // tile 2j, S <- scores(2j+1)
    Ha_e[0].u = *(const uint4*)(hp + 4096);   // H tile 2j+2
    Ha_e[1].u = *(const uint4*)(hp + 4352);
    Ha_e[2].u = *(const uint4*)(hp + 5120);
    Ha_e[3].u = *(const uint4*)(hp + 5376);
    F1.u = *(const uint4*)(fp + 768);         // F tile 2j+3
    body(Ha_o, F0, true);                     // tile 2j+1, S <- scores(2j+2)
    fp += 512;
    hp += 4096;
  }
  // tail: Ha_e holds H(30), F1 holds F(31), S holds scores(30)
  Ha_o[0].u = *(const uint4*)(hp + 2048);     // H tile 31
  Ha_o[1].u = *(const uint4*)(hp + 2304);
  Ha_o[2].u = *(const uint4*)(hp + 3072);
  Ha_o[3].u = *(const uint4*)(hp + 3328);
  body(Ha_e, F1, true);                       // tile 30, S <- scores(31)
  body(Ha_o, F1, false);                      // tile 31 (no produce)

  // wave-local denominator (both halves), then stash partials (bf16 pairs)
  lp += __shfl_xor(lp, 32, 64);
  if (hh == 0) lred[wave][ml] = lp;
#pragma unroll
  for (int r = 0; r < 8; ++r) {
    const int c0 = ((2 * r) & 3) + 8 * (r >> 1) + 4 * hh;
    *(unsigned*)&Opart[wave][ml][c0] = packbf(O0[2 * r], O0[2 * r + 1]);
    *(unsigned*)&Opart[wave][ml][c0 + 32] = packbf(O1[2 * r], O1[2 * r + 1]);
  }
  __syncthreads();
  if (tid < 32)
    lsum[tid] = (lred[0][tid] + lred[1][tid]) + (lred[2][tid] + lred[3][tid]);
  __syncthreads();

  // epilogue: thread owns c = tid>>2, m = (tid&3)*8 .. +8 (vectorized global)
  const int c = tid >> 2;
  const int m0l = (tid & 3) << 3;
  const float gam = gamma[0];
  float a[8];
#pragma unroll
  for (int j = 0; j < 8; ++j) a[j] = 0.f;
#pragma unroll
  for (int w = 0; w < 4; ++w)
#pragma unroll
    for (int j = 0; j < 8; ++j) a[j] += b2f(Opart[w][m0l + j][c]);

  const f32x4 l0 = *(const f32x4*)&lsum[m0l];
  const f32x4 l1 = *(const f32x4*)&lsum[m0l + 4];
  const size_t oi = (((size_t)b * 64 + c) << 12) + m32 + m0l;
  f32x4 xo0 = *(const f32x4*)(x + oi);
  f32x4 xo1 = *(const f32x4*)(x + oi + 4);
#pragma unroll
  for (int j = 0; j < 4; ++j) {
    xo0[j] += gam / l0[j] * a[j];
    xo1[j] += gam / l1[j] * a[j + 4];
  }
  *(f32x4*)(out + oi) = xo0;
  *(f32x4*)(out + oi + 4) = xo1;
}

extern "C" void kernel_launch(void* const* d_in, const int* in_sizes, int n_in,
                              void* d_out, int out_size, void* d_ws, size_t ws_size,
                              hipStream_t stream) {
  (void)in_sizes; (void)n_in; (void)out_size; (void)ws_size;
  const float* x = (const float*)d_in[0];
  const float* wq = (const float*)d_in[1];
  const float* wk = (const float*)d_in[2];
  const float* wv = (const float*)d_in[3];
  const float* gamma = (const float*)d_in[4];
  float* out = (float*)d_out;

  // workspace: f_t [8][4096][8] bf16, g_t same, h_blk [8][512][64][8] bf16
  unsigned short* f_t = (unsigned short*)d_ws;
  unsigned short* g_t = f_t + (size_t)8 * 4096 * 8;
  unsigned short* h = g_t + (size_t)8 * 4096 * 8;

  proj_kernel<<<512, 256, 0, stream>>>(x, wq, wk, wv, f_t, g_t, h);
  attn_kernel<<<1024, 256, 0, stream>>>(f_t, g_t, h, x, gamma, out);
}

// Round 4
// 102.936 us; speedup vs baseline: 1.2961x; 1.0252x over previous
//
#include <hip/hip_runtime.h>
#include <hip/hip_bf16.h>

typedef __bf16 bf16x8 __attribute__((ext_vector_type(8)));
typedef float f32x4 __attribute__((ext_vector_type(4)));
typedef float f32x16 __attribute__((ext_vector_type(16)));
typedef unsigned int uint2v __attribute__((ext_vector_type(2)));

#define MFMA16 __builtin_amdgcn_mfma_f32_16x16x32_bf16
#define MFMA32 __builtin_amdgcn_mfma_f32_32x32x16_bf16

__device__ __forceinline__ unsigned short f2b(float f) {
  unsigned int u = __float_as_uint(f);
  u += 0x7FFFu + ((u >> 16) & 1u);
  return (unsigned short)(u >> 16);
}

__device__ __forceinline__ float b2f(unsigned short s) {
  return __uint_as_float(((unsigned)s) << 16);
}

union U128 {
  uint4 u;
  unsigned short s[8];
  bf16x8 b;
};

union BPack {
  __hip_bfloat162 h2;
  unsigned u;
};

__device__ __forceinline__ unsigned packbf(float a, float b) {
  BPack p;
  p.h2 = __float22bfloat162_rn(make_float2(a, b));
  return p.u;
}

// ---------------- projection via MFMA ----------------
// grid 512 = (b = blk&7, n0 = 64-tile). block 256 (4 waves).
// Y[96 pad][4096] = W[96x64] X[64x4096] per batch, bf16 MFMA 16x16x32.
// wq rows pre-scaled by log2(e) so attention uses native exp2.
// h stored BLOCKED: h_blk[b][n>>3][c][n&7].
// R11: packed stores. Old path: 20 scalar 2-byte global stores/thread
// (16 B lane stride — worst-case write combining; proj was store-bound).
// New: f/g = one 8 B store (rt=0's 4 accs are 4 consecutive r at one n);
// h bounced through LDS hT[64][72] then 2x16 B stores, 64 lanes contiguous.
__global__ __launch_bounds__(256, 2) void proj_kernel(
    const float* __restrict__ x, const float* __restrict__ wq,
    const float* __restrict__ wk, const float* __restrict__ wv_w,
    unsigned short* __restrict__ f_t, unsigned short* __restrict__ g_t,
    unsigned short* __restrict__ h_out) {
  __shared__ unsigned short xT[64 * 64];
  __shared__ unsigned short wT[96 * 72];
  __shared__ unsigned short hT[64 * 72];  // [c][n], pad 72 (16B-aligned rows)

  const int tid = (int)threadIdx.x;
  const int wvp = tid >> 6;
  const int lane = tid & 63;
  const int b = (int)blockIdx.x & 7;
  const int n0 = ((int)blockIdx.x >> 3) << 6;

  // ---- stage xT: thread loads 16 c's for n=lane, packs, swizzled write ----
  {
    const float* xb = x + ((size_t)b << 18) + n0 + lane;
    const int c0 = wvp * 16;
    float xv[16];
#pragma unroll
    for (int cc = 0; cc < 16; ++cc) xv[cc] = xb[(size_t)(c0 + cc) << 12];
#pragma unroll
    for (int p = 0; p < 4; ++p) {
      const int c = c0 + 4 * p;
      uint2 d;
      d.x = packbf(xv[4 * p + 0], xv[4 * p + 1]);
      d.y = packbf(xv[4 * p + 2], xv[4 * p + 3]);
      const int g = c >> 3;
      const int idx = lane * 64 + (((g ^ (lane & 7)) << 3) | (((c >> 2) & 1) << 2));
      *(uint2*)&xT[idx] = d;
    }
  }
  // ---- stage wT (80 rows of 64, bf16); wq scaled by log2(e) ----
#pragma unroll
  for (int i = 0; i < 20; ++i) {
    const int idx = i * 256 + tid;
    const float wval = (idx < 512) ? wq[idx] * 1.44269504f
                     : (idx < 1024) ? wk[idx - 512]
                                    : wv_w[idx - 1024];
    wT[(idx >> 6) * 72 + (idx & 63)] = f2b(wval);
  }
  __syncthreads();

  // ---- compute ----
  const int t = lane & 15, q = lane >> 4;
  const int nloc = wvp * 16 + t;
  U128 Bf[2];
#pragma unroll
  for (int kp = 0; kp < 2; ++kp) {
    const int g = kp * 4 + q;
    Bf[kp].u = *(const uint4*)&xT[nloc * 64 + ((g ^ (nloc & 7)) << 3)];
  }
  const int nabs = n0 + nloc;

  // rt = 0: f (r0-7) / g (r8-15): thread owns 4 consecutive r at one n ->
  // single packed 8 B store.
  {
    f32x4 acc = {0.f, 0.f, 0.f, 0.f};
#pragma unroll
    for (int kp = 0; kp < 2; ++kp) {
      U128 Af;
      Af.u = *(const uint4*)&wT[t * 72 + ((kp * 4 + q) << 3)];
      acc = MFMA16(Af.b, Bf[kp].b, acc, 0, 0, 0);
    }
    uint2 d;
    d.x = packbf(acc[0], acc[1]);
    d.y = packbf(acc[2], acc[3]);
    unsigned short* dst = (q & 2) ? g_t : f_t;
    *(uint2*)&dst[((size_t)((b << 12) + nabs) << 3) + ((q & 1) << 2)] = d;
  }
  // rt = 1..4: h rows c = (rt-1)*16 + 4q + reg -> LDS (scalar bf16 writes,
  // cheap), transposed readback below.
#pragma unroll
  for (int rt = 1; rt < 5; ++rt) {
    f32x4 acc = {0.f, 0.f, 0.f, 0.f};
#pragma unroll
    for (int kp = 0; kp < 2; ++kp) {
      U128 Af;
      Af.u = *(const uint4*)&wT[(rt * 16 + t) * 72 + ((kp * 4 + q) << 3)];
      acc = MFMA16(Af.b, Bf[kp].b, acc, 0, 0, 0);
    }
    const int cbase = (rt - 1) * 16 + 4 * q;
#pragma unroll
    for (int reg = 0; reg < 4; ++reg)
      hT[(cbase + reg) * 72 + nloc] = f2b(acc[reg]);
  }
  __syncthreads();

  // packed h store: thread owns row c = tid&63, n-quarter = tid>>6.
  // h_out[b][n>>3][c][n&7]: 16 consecutive n = 2 n-blocks = 2x16 B stores;
  // lanes (consecutive c) are 16 B-stride contiguous -> 1 KB per instruction.
  {
    const int hc = tid & 63;
    const int hw = tid >> 6;
    const uint4 v0 = *(const uint4*)&hT[hc * 72 + hw * 16];
    const uint4 v1 = *(const uint4*)&hT[hc * 72 + hw * 16 + 8];
    const size_t hbase =
        ((size_t)b << 18) + ((size_t)((n0 + hw * 16) >> 3) << 9) + (hc << 3);
    *(uint4*)&h_out[hbase] = v0;
    *(uint4*)&h_out[hbase + 512] = v1;
  }
}

// ---------------- flash attention ------------------------------------------
// grid 1024 = (b = blk&7, m32-tile). block 256 (4 waves, independent).
// R10: in-place score pipeline (one persistent f32x16 S; produce-MFMA for
// tile k+1 overwrites S after body k's exps read it).
// R11: LDS cut 17.9 KB -> 9.1 KB via m-sliced epilogue (Opart[4][16][66],
// two stash/drain phases). Theory: workgroup LDS budget capped residency at
// 3 blocks/CU (occupancy counter ~26%); 9.1 KB guarantees the full
// 4 blocks/CU the grid offers. Numerics bit-identical.
__global__ __launch_bounds__(256, 4) void attn_kernel(
    const unsigned short* __restrict__ f_t, const unsigned short* __restrict__ g_t,
    const unsigned short* __restrict__ h, const float* __restrict__ x,
    const float* __restrict__ gamma, float* __restrict__ out) {
  __shared__ unsigned short Opart[4][16][66];  // [wave][m-half][c], 8.45 KB
  __shared__ float lred[4][32];
  __shared__ float lsum[32];

  const int tid = (int)threadIdx.x;
  const int wave = tid >> 6;
  const int lane = tid & 63;
  const int ml = lane & 31;
  const int hh = lane >> 5;

  const int b = (int)blockIdx.x & 7;
  const int m32 = ((int)blockIdx.x >> 3) << 5;

  const unsigned short* fb = f_t + ((size_t)b << 15);
  const unsigned short* hb = h + ((size_t)b << 18);  // blocked layout

  U128 G;
  G.u = make_uint4(0u, 0u, 0u, 0u);
  if (hh == 0) G.u = *(const uint4*)(g_t + ((size_t)((b << 12) + m32 + ml) << 3));

  f32x16 O0 = {}, O1 = {};
  float lp = 0.f;
  const f32x16 ZC = {};  // persistent zero C operand

  const int nbase = wave << 10;

  const unsigned short* fp = fb + ((size_t)(nbase + ml) << 3);      // +512/iter
  const unsigned short* hp = hb + ((nbase >> 3) << 9) + (hh << 9) + (ml << 3);  // +4096/iter

  // fragment slots: F ping-pong (2), H ping-pong (2x4), ONE persistent S
  U128 F0, F1, Ha_e[4], Ha_o[4];
  f32x16 S;

  // prologue: F tiles 0,1; H tile 0; S = scores(tile 0)
  F0.u = *(const uint4*)(fp);
  F1.u = *(const uint4*)(fp + 256);
  Ha_e[0].u = *(const uint4*)(hp);
  Ha_e[1].u = *(const uint4*)(hp + 256);
  Ha_e[2].u = *(const uint4*)(hp + 1024);
  Ha_e[3].u = *(const uint4*)(hp + 1280);
  __builtin_amdgcn_s_setprio(1);
  S = MFMA32(F0.b, G.b, ZC, 0, 0, 0);
  __builtin_amdgcn_s_setprio(0);

  // body: exps consume S (tile k); if produce, S <- scores(tile k+1) from Fn
  // (in place — S is dead after the exps); then pack + PV with Hv (tile k).
  auto body = [&](const U128* Hv, const U128& Fn, bool produce) {
    float e[16];
#pragma unroll
    for (int r = 0; r < 16; ++r) e[r] = __builtin_amdgcn_exp2f(S[r]);
    if (produce) {
      __builtin_amdgcn_s_setprio(1);
      S = MFMA32(Fn.b, G.b, ZC, 0, 0, 0);
      __builtin_amdgcn_s_setprio(0);
    }
    lp += (((e[0] + e[1]) + (e[2] + e[3])) + ((e[4] + e[5]) + (e[6] + e[7]))) +
          (((e[8] + e[9]) + (e[10] + e[11])) + ((e[12] + e[13]) + (e[14] + e[15])));
#pragma unroll
    for (int kt = 0; kt < 2; ++kt) {
      const unsigned A0 = packbf(e[8 * kt + 0], e[8 * kt + 1]);
      const unsigned A1 = packbf(e[8 * kt + 2], e[8 * kt + 3]);
      const unsigned B0 = packbf(e[8 * kt + 4], e[8 * kt + 5]);
      const unsigned B1 = packbf(e[8 * kt + 6], e[8 * kt + 7]);
      const uint2v r0 = __builtin_amdgcn_permlane32_swap(A0, B0, false, false);
      const uint2v r1 = __builtin_amdgcn_permlane32_swap(A1, B1, false, false);
      U128 P;
      P.u.x = r0[0];
      P.u.y = r1[0];
      P.u.z = r0[1];
      P.u.w = r1[1];
      __builtin_amdgcn_s_setprio(1);
      O0 = MFMA32(Hv[2 * kt + 0].b, P.b, O0, 0, 0, 0);
      O1 = MFMA32(Hv[2 * kt + 1].b, P.b, O1, 0, 0, 0);
      __builtin_amdgcn_s_setprio(0);
    }
  };

  // main loop: tiles 2j, 2j+1 for j=0..14; tiles 30,31 peeled.
#pragma unroll 1
  for (int j = 0; j < 15; ++j) {
    Ha_o[0].u = *(const uint4*)(hp + 2048);   // H tile 2j+1
    Ha_o[1].u = *(const uint4*)(hp + 2304);
    Ha_o[2].u = *(const uint4*)(hp + 3072);
    Ha_o[3].u = *(const uint4*)(hp + 3328);
    F0.u = *(const uint4*)(fp + 512);         // F tile 2j+2
    body(Ha_e, F1, true);                     // tile 2j, S <- scores(2j+1)
    Ha_e[0].u = *(const uint4*)(hp + 4096);   // H tile 2j+2
    Ha_e[1].u = *(const uint4*)(hp + 4352);
    Ha_e[2].u = *(const uint4*)(hp + 5120);
    Ha_e[3].u = *(const uint4*)(hp + 5376);
    F1.u = *(const uint4*)(fp + 768);         // F tile 2j+3
    body(Ha_o, F0, true);                     // tile 2j+1, S <- scores(2j+2)
    fp += 512;
    hp += 4096;
  }
  // tail: Ha_e holds H(30), F1 holds F(31), S holds scores(30)
  Ha_o[0].u = *(const uint4*)(hp + 2048);     // H tile 31
  Ha_o[1].u = *(const uint4*)(hp + 2304);
  Ha_o[2].u = *(const uint4*)(hp + 3072);
  Ha_o[3].u = *(const uint4*)(hp + 3328);
  body(Ha_e, F1, true);                       // tile 30, S <- scores(31)
  body(Ha_o, F1, false);                      // tile 31 (no produce)

  // ---- epilogue: m-sliced (two 16-row phases share one 8.45 KB Opart) ----
  lp += __shfl_xor(lp, 32, 64);
  if (hh == 0) lred[wave][ml] = lp;

  const float gam = gamma[0];

  auto stash = [&](int p) {
    if ((ml >> 4) == p) {
      const int mi = ml & 15;
#pragma unroll
      for (int r = 0; r < 8; ++r) {
        const int c0 = ((2 * r) & 3) + 8 * (r >> 1) + 4 * hh;
        *(unsigned*)&Opart[wave][mi][c0] = packbf(O0[2 * r], O0[2 * r + 1]);
        *(unsigned*)&Opart[wave][mi][c0 + 32] = packbf(O1[2 * r], O1[2 * r + 1]);
      }
    }
  };
  auto drain = [&](int p) {
    const int c = tid >> 2;
    const int m4 = (tid & 3) << 2;
    float a0 = 0.f, a1 = 0.f, a2 = 0.f, a3 = 0.f;
#pragma unroll
    for (int w = 0; w < 4; ++w) {
      a0 += b2f(Opart[w][m4 + 0][c]);
      a1 += b2f(Opart[w][m4 + 1][c]);
      a2 += b2f(Opart[w][m4 + 2][c]);
      a3 += b2f(Opart[w][m4 + 3][c]);
    }
    const f32x4 l = *(const f32x4*)&lsum[p * 16 + m4];
    const size_t oi = (((size_t)b * 64 + c) << 12) + m32 + p * 16 + m4;
    f32x4 xo = *(const f32x4*)(x + oi);
    xo[0] += gam / l[0] * a0;
    xo[1] += gam / l[1] * a1;
    xo[2] += gam / l[2] * a2;
    xo[3] += gam / l[3] * a3;
    *(f32x4*)(out + oi) = xo;
  };

  stash(0);
  __syncthreads();  // lred + phase-0 Opart visible
  if (tid < 32)
    lsum[tid] = (lred[0][tid] + lred[1][tid]) + (lred[2][tid] + lred[3][tid]);
  __syncthreads();  // lsum visible
  drain(0);
  __syncthreads();  // phase-0 reads done before overwrite
  stash(1);
  __syncthreads();  // phase-1 Opart visible
  drain(1);
}

extern "C" void kernel_launch(void* const* d_in, const int* in_sizes, int n_in,
                              void* d_out, int out_size, void* d_ws, size_t ws_size,
                              hipStream_t stream) {
  (void)in_sizes; (void)n_in; (void)out_size; (void)ws_size;
  const float* x = (const float*)d_in[0];
  const float* wq = (const float*)d_in[1];
  const float* wk = (const float*)d_in[2];
  const float* wv = (const float*)d_in[3];
  const float* gamma = (const float*)d_in[4];
  float* out = (float*)d_out;

  // workspace: f_t [8][4096][8] bf16, g_t same, h_blk [8][512][64][8] bf16
  unsigned short* f_t = (unsigned short*)d_ws;
  unsigned short* g_t = f_t + (size_t)8 * 4096 * 8;
  unsigned short* h = g_t + (size_t)8 * 4096 * 8;

  proj_kernel<<<512, 256, 0, stream>>>(x, wq, wk, wv, f_t, g_t, h);
  attn_kernel<<<1024, 256, 0, stream>>>(f_t, g_t, h, x, gamma, out);
}

// Round 5
// 101.731 us; speedup vs baseline: 1.3114x; 1.0118x over previous
//
#include <hip/hip_runtime.h>
#include <hip/hip_bf16.h>

typedef __bf16 bf16x8 __attribute__((ext_vector_type(8)));
typedef float f32x4 __attribute__((ext_vector_type(4)));
typedef float f32x16 __attribute__((ext_vector_type(16)));
typedef unsigned int uint2v __attribute__((ext_vector_type(2)));

#define MFMA16 __builtin_amdgcn_mfma_f32_16x16x32_bf16
#define MFMA32 __builtin_amdgcn_mfma_f32_32x32x16_bf16

__device__ __forceinline__ unsigned short f2b(float f) {
  unsigned int u = __float_as_uint(f);
  u += 0x7FFFu + ((u >> 16) & 1u);
  return (unsigned short)(u >> 16);
}

__device__ __forceinline__ float b2f(unsigned short s) {
  return __uint_as_float(((unsigned)s) << 16);
}

union U128 {
  uint4 u;
  unsigned short s[8];
  bf16x8 b;
};

union BPack {
  __hip_bfloat162 h2;
  unsigned u;
};

__device__ __forceinline__ unsigned packbf(float a, float b) {
  BPack p;
  p.h2 = __float22bfloat162_rn(make_float2(a, b));
  return p.u;
}

// ---------------- projection via MFMA ----------------
// grid 512 = (b = blk&7, n0 = 64-tile). block 256 (4 waves).
// Y[96 pad][4096] = W[96x64] X[64x4096] per batch, bf16 MFMA 16x16x32.
// wq rows pre-scaled by log2(e) so attention uses native exp2.
// h stored BLOCKED: h_blk[b][n>>3][c][n&7].
// R11: packed stores (f/g one 8 B store; h bounced via LDS, 2x16 B stores).
__global__ __launch_bounds__(256, 2) void proj_kernel(
    const float* __restrict__ x, const float* __restrict__ wq,
    const float* __restrict__ wk, const float* __restrict__ wv_w,
    unsigned short* __restrict__ f_t, unsigned short* __restrict__ g_t,
    unsigned short* __restrict__ h_out) {
  __shared__ unsigned short xT[64 * 64];
  __shared__ unsigned short wT[96 * 72];
  __shared__ unsigned short hT[64 * 72];  // [c][n], pad 72 (16B-aligned rows)

  const int tid = (int)threadIdx.x;
  const int wvp = tid >> 6;
  const int lane = tid & 63;
  const int b = (int)blockIdx.x & 7;
  const int n0 = ((int)blockIdx.x >> 3) << 6;

  // ---- stage xT: thread loads 16 c's for n=lane, packs, swizzled write ----
  {
    const float* xb = x + ((size_t)b << 18) + n0 + lane;
    const int c0 = wvp * 16;
    float xv[16];
#pragma unroll
    for (int cc = 0; cc < 16; ++cc) xv[cc] = xb[(size_t)(c0 + cc) << 12];
#pragma unroll
    for (int p = 0; p < 4; ++p) {
      const int c = c0 + 4 * p;
      uint2 d;
      d.x = packbf(xv[4 * p + 0], xv[4 * p + 1]);
      d.y = packbf(xv[4 * p + 2], xv[4 * p + 3]);
      const int g = c >> 3;
      const int idx = lane * 64 + (((g ^ (lane & 7)) << 3) | (((c >> 2) & 1) << 2));
      *(uint2*)&xT[idx] = d;
    }
  }
  // ---- stage wT (80 rows of 64, bf16); wq scaled by log2(e) ----
#pragma unroll
  for (int i = 0; i < 20; ++i) {
    const int idx = i * 256 + tid;
    const float wval = (idx < 512) ? wq[idx] * 1.44269504f
                     : (idx < 1024) ? wk[idx - 512]
                                    : wv_w[idx - 1024];
    wT[(idx >> 6) * 72 + (idx & 63)] = f2b(wval);
  }
  __syncthreads();

  // ---- compute ----
  const int t = lane & 15, q = lane >> 4;
  const int nloc = wvp * 16 + t;
  U128 Bf[2];
#pragma unroll
  for (int kp = 0; kp < 2; ++kp) {
    const int g = kp * 4 + q;
    Bf[kp].u = *(const uint4*)&xT[nloc * 64 + ((g ^ (nloc & 7)) << 3)];
  }
  const int nabs = n0 + nloc;

  // rt = 0: f (r0-7) / g (r8-15): one packed 8 B store per thread.
  {
    f32x4 acc = {0.f, 0.f, 0.f, 0.f};
#pragma unroll
    for (int kp = 0; kp < 2; ++kp) {
      U128 Af;
      Af.u = *(const uint4*)&wT[t * 72 + ((kp * 4 + q) << 3)];
      acc = MFMA16(Af.b, Bf[kp].b, acc, 0, 0, 0);
    }
    uint2 d;
    d.x = packbf(acc[0], acc[1]);
    d.y = packbf(acc[2], acc[3]);
    unsigned short* dst = (q & 2) ? g_t : f_t;
    *(uint2*)&dst[((size_t)((b << 12) + nabs) << 3) + ((q & 1) << 2)] = d;
  }
  // rt = 1..4: h rows -> LDS, transposed packed readback below.
#pragma unroll
  for (int rt = 1; rt < 5; ++rt) {
    f32x4 acc = {0.f, 0.f, 0.f, 0.f};
#pragma unroll
    for (int kp = 0; kp < 2; ++kp) {
      U128 Af;
      Af.u = *(const uint4*)&wT[(rt * 16 + t) * 72 + ((kp * 4 + q) << 3)];
      acc = MFMA16(Af.b, Bf[kp].b, acc, 0, 0, 0);
    }
    const int cbase = (rt - 1) * 16 + 4 * q;
#pragma unroll
    for (int reg = 0; reg < 4; ++reg)
      hT[(cbase + reg) * 72 + nloc] = f2b(acc[reg]);
  }
  __syncthreads();

  // packed h store: thread owns row c = tid&63, n-quarter = tid>>6.
  {
    const int hc = tid & 63;
    const int hw = tid >> 6;
    const uint4 v0 = *(const uint4*)&hT[hc * 72 + hw * 16];
    const uint4 v1 = *(const uint4*)&hT[hc * 72 + hw * 16 + 8];
    const size_t hbase =
        ((size_t)b << 18) + ((size_t)((n0 + hw * 16) >> 3) << 9) + (hc << 3);
    *(uint4*)&h_out[hbase] = v0;
    *(uint4*)&h_out[hbase + 512] = v1;
  }
}

// ---------------- flash attention ------------------------------------------
// R12: m64 blocking. grid 512 = (b = blk&7, m64-tile). block 256 (4 waves,
// independent; wave = n-quarter). Each block computes TWO m32 G-tiles
// (G0/G1), so every H/F fragment loaded serves 2x the score/PV work:
// H L2 traffic 512 MB -> 256 MB (the ~15 us per-XCD-L2 floor halves).
// b = blk&7 pins batch b to XCD b (h tile stays L2-resident).
// Per wave per n-tile: 2 score MFMA32 (S0,S1 in-place pipeline, R10), 2x16
// exp2, 2x(pack+permlane32_swap), 8 PV MFMA32 into O00/O01/O10/O11.
// launch_bounds(256,2): ~180 VGPR fits 256-reg budget, 2 blocks/CU (= grid).
// Epilogue: 4 m16-phases through one 8.45 KB Opart. Numerics bit-identical.
__global__ __launch_bounds__(256, 2) void attn_kernel(
    const unsigned short* __restrict__ f_t, const unsigned short* __restrict__ g_t,
    const unsigned short* __restrict__ h, const float* __restrict__ x,
    const float* __restrict__ gamma, float* __restrict__ out) {
  __shared__ unsigned short Opart[4][16][66];  // [wave][m-slice][c], 8.45 KB
  __shared__ float lred[4][64];
  __shared__ float lsum[64];

  const int tid = (int)threadIdx.x;
  const int wave = tid >> 6;
  const int lane = tid & 63;
  const int ml = lane & 31;
  const int hh = lane >> 5;

  const int b = (int)blockIdx.x & 7;
  const int m0 = ((int)blockIdx.x >> 3) << 6;  // m64 tile base

  const unsigned short* fb = f_t + ((size_t)b << 15);
  const unsigned short* hb = h + ((size_t)b << 18);  // blocked layout

  U128 G0, G1;
  G0.u = make_uint4(0u, 0u, 0u, 0u);
  G1.u = make_uint4(0u, 0u, 0u, 0u);
  if (hh == 0) {
    G0.u = *(const uint4*)(g_t + ((size_t)((b << 12) + m0 + ml) << 3));
    G1.u = *(const uint4*)(g_t + ((size_t)((b << 12) + m0 + 32 + ml) << 3));
  }

  f32x16 O00 = {}, O01 = {}, O10 = {}, O11 = {};
  float lp0 = 0.f, lp1 = 0.f;
  const f32x16 ZC = {};

  const int nbase = wave << 10;

  const unsigned short* fp = fb + ((size_t)(nbase + ml) << 3);      // +512/2 tiles
  const unsigned short* hp = hb + ((nbase >> 3) << 9) + (hh << 9) + (ml << 3);  // +4096/2 tiles

  // fragment slots: F ping-pong, H ping-pong, TWO persistent S (in-place)
  U128 F0, F1, Ha_e[4], Ha_o[4];
  f32x16 S0, S1;

  // prologue: F tiles 0,1; H tile 0; S0/S1 = scores(tile 0)
  F0.u = *(const uint4*)(fp);
  F1.u = *(const uint4*)(fp + 256);
  Ha_e[0].u = *(const uint4*)(hp);
  Ha_e[1].u = *(const uint4*)(hp + 256);
  Ha_e[2].u = *(const uint4*)(hp + 1024);
  Ha_e[3].u = *(const uint4*)(hp + 1280);
  __builtin_amdgcn_s_setprio(1);
  S0 = MFMA32(F0.b, G0.b, ZC, 0, 0, 0);
  S1 = MFMA32(F0.b, G1.b, ZC, 0, 0, 0);
  __builtin_amdgcn_s_setprio(0);

  // half: exps consume S (tile k, this G); if produce, S <- scores(k+1)
  // in place; pack + PV into this m-tile's O pair using shared H fragments.
  auto half = [&](f32x16& S, const U128& G, float& lp, f32x16& Oa, f32x16& Ob,
                  const U128* Hv, const U128& Fn, bool produce) {
    float e[16];
#pragma unroll
    for (int r = 0; r < 16; ++r) e[r] = __builtin_amdgcn_exp2f(S[r]);
    if (produce) {
      __builtin_amdgcn_s_setprio(1);
      S = MFMA32(Fn.b, G.b, ZC, 0, 0, 0);
      __builtin_amdgcn_s_setprio(0);
    }
    lp += (((e[0] + e[1]) + (e[2] + e[3])) + ((e[4] + e[5]) + (e[6] + e[7]))) +
          (((e[8] + e[9]) + (e[10] + e[11])) + ((e[12] + e[13]) + (e[14] + e[15])));
#pragma unroll
    for (int kt = 0; kt < 2; ++kt) {
      const unsigned A0 = packbf(e[8 * kt + 0], e[8 * kt + 1]);
      const unsigned A1 = packbf(e[8 * kt + 2], e[8 * kt + 3]);
      const unsigned B0 = packbf(e[8 * kt + 4], e[8 * kt + 5]);
      const unsigned B1 = packbf(e[8 * kt + 6], e[8 * kt + 7]);
      const uint2v r0 = __builtin_amdgcn_permlane32_swap(A0, B0, false, false);
      const uint2v r1 = __builtin_amdgcn_permlane32_swap(A1, B1, false, false);
      U128 P;
      P.u.x = r0[0];
      P.u.y = r1[0];
      P.u.z = r0[1];
      P.u.w = r1[1];
      __builtin_amdgcn_s_setprio(1);
      Oa = MFMA32(Hv[2 * kt + 0].b, P.b, Oa, 0, 0, 0);
      Ob = MFMA32(Hv[2 * kt + 1].b, P.b, Ob, 0, 0, 0);
      __builtin_amdgcn_s_setprio(0);
    }
  };
  auto body = [&](const U128* Hv, const U128& Fn, bool produce) {
    half(S0, G0, lp0, O00, O01, Hv, Fn, produce);
    half(S1, G1, lp1, O10, O11, Hv, Fn, produce);
  };

  // main loop: tiles 2j, 2j+1 for j=0..14; tiles 30,31 peeled.
#pragma unroll 1
  for (int j = 0; j < 15; ++j) {
    Ha_o[0].u = *(const uint4*)(hp + 2048);   // H tile 2j+1
    Ha_o[1].u = *(const uint4*)(hp + 2304);
    Ha_o[2].u = *(const uint4*)(hp + 3072);
    Ha_o[3].u = *(const uint4*)(hp + 3328);
    F0.u = *(const uint4*)(fp + 512);         // F tile 2j+2
    body(Ha_e, F1, true);                     // tile 2j
    Ha_e[0].u = *(const uint4*)(hp + 4096);   // H tile 2j+2
    Ha_e[1].u = *(const uint4*)(hp + 4352);
    Ha_e[2].u = *(const uint4*)(hp + 5120);
    Ha_e[3].u = *(const uint4*)(hp + 5376);
    F1.u = *(const uint4*)(fp + 768);         // F tile 2j+3
    body(Ha_o, F0, true);                     // tile 2j+1
    fp += 512;
    hp += 4096;
  }
  // tail: Ha_e holds H(30), F1 holds F(31)
  Ha_o[0].u = *(const uint4*)(hp + 2048);     // H tile 31
  Ha_o[1].u = *(const uint4*)(hp + 2304);
  Ha_o[2].u = *(const uint4*)(hp + 3072);
  Ha_o[3].u = *(const uint4*)(hp + 3328);
  body(Ha_e, F1, true);                       // tile 30
  body(Ha_o, F1, false);                      // tile 31 (no produce)

  // ---- epilogue: 4 m16-phases through one Opart buffer ----
  lp0 += __shfl_xor(lp0, 32, 64);
  lp1 += __shfl_xor(lp1, 32, 64);
  if (hh == 0) {
    lred[wave][ml] = lp0;
    lred[wave][32 + ml] = lp1;
  }

  const float gam = gamma[0];

  // stash m-slice p (16 rows): p<2 -> tile0 (O00/O01), else tile1 (O10/O11)
  auto stash = [&](int p, const f32x16& Oa, const f32x16& Ob) {
    if ((ml >> 4) == (p & 1)) {
      const int mi = ml & 15;
#pragma unroll
      for (int r = 0; r < 8; ++r) {
        const int c0 = ((2 * r) & 3) + 8 * (r >> 1) + 4 * hh;
        *(unsigned*)&Opart[wave][mi][c0] = packbf(Oa[2 * r], Oa[2 * r + 1]);
        *(unsigned*)&Opart[wave][mi][c0 + 32] = packbf(Ob[2 * r], Ob[2 * r + 1]);
      }
    }
  };
  auto drain = [&](int p) {
    const int c = tid >> 2;
    const int m4 = (tid & 3) << 2;
    float a0 = 0.f, a1 = 0.f, a2 = 0.f, a3 = 0.f;
#pragma unroll
    for (int w = 0; w < 4; ++w) {
      a0 += b2f(Opart[w][m4 + 0][c]);
      a1 += b2f(Opart[w][m4 + 1][c]);
      a2 += b2f(Opart[w][m4 + 2][c]);
      a3 += b2f(Opart[w][m4 + 3][c]);
    }
    const f32x4 l = *(const f32x4*)&lsum[p * 16 + m4];
    const size_t oi = (((size_t)b * 64 + c) << 12) + m0 + p * 16 + m4;
    f32x4 xo = *(const f32x4*)(x + oi);
    xo[0] += gam / l[0] * a0;
    xo[1] += gam / l[1] * a1;
    xo[2] += gam / l[2] * a2;
    xo[3] += gam / l[3] * a3;
    *(f32x4*)(out + oi) = xo;
  };

  stash(0, O00, O01);
  __syncthreads();  // lred + phase-0 Opart visible
  if (tid < 64)
    lsum[tid] = (lred[0][tid] + lred[1][tid]) + (lred[2][tid] + lred[3][tid]);
  __syncthreads();  // lsum visible
  drain(0);
  __syncthreads();
  stash(1, O00, O01);
  __syncthreads();
  drain(1);
  __syncthreads();
  stash(2, O10, O11);
  __syncthreads();
  drain(2);
  __syncthreads();
  stash(3, O10, O11);
  __syncthreads();
  drain(3);
}

extern "C" void kernel_launch(void* const* d_in, const int* in_sizes, int n_in,
                              void* d_out, int out_size, void* d_ws, size_t ws_size,
                              hipStream_t stream) {
  (void)in_sizes; (void)n_in; (void)out_size; (void)ws_size;
  const float* x = (const float*)d_in[0];
  const float* wq = (const float*)d_in[1];
  const float* wk = (const float*)d_in[2];
  const float* wv = (const float*)d_in[3];
  const float* gamma = (const float*)d_in[4];
  float* out = (float*)d_out;

  // workspace: f_t [8][4096][8] bf16, g_t same, h_blk [8][512][64][8] bf16
  unsigned short* f_t = (unsigned short*)d_ws;
  unsigned short* g_t = f_t + (size_t)8 * 4096 * 8;
  unsigned short* h = g_t + (size_t)8 * 4096 * 8;

  proj_kernel<<<512, 256, 0, stream>>>(x, wq, wk, wv, f_t, g_t, h);
  attn_kernel<<<512, 256, 0, stream>>>(f_t, g_t, h, x, gamma, out);
}